// Round 7
// baseline (180.551 us; speedup 1.0000x reference)
//
#include <hip/hip_runtime.h>
#include <math.h>

constexpr int NB = 8, NS = 2048, ND = 65;
constexpr int KP = 104;     // padded K stride for x conv (bf16 elems)
constexpr int VD = 80;      // padded d rows for V^T
constexpr size_t OUTSZ = (size_t)NB * NS * ND;
constexpr size_t CONVN = (size_t)NB * NS * KP;   // x conv elems per array
constexpr size_t VTN   = (size_t)NB * VD * NS;   // V^T elems per array

typedef short short8 __attribute__((ext_vector_type(8)));
typedef float f32x4 __attribute__((ext_vector_type(4)));

__device__ __forceinline__ ushort f2bf(float f) {
    uint u = __float_as_uint(f);
    return (ushort)((u + 0x7fffu + ((u >> 16) & 1u)) >> 16);   // RNE
}
__device__ __forceinline__ float bf2f(ushort h) {
    return __uint_as_float((uint)h << 16);
}

// ---------------------------------------------------------------------------
// k0x: x fp32 -> (hi, lo) bf16 split arrays, K padded 65->104 with zeros.
// ---------------------------------------------------------------------------
__global__ __launch_bounds__(256)
void k0_convert(const float* __restrict__ x, ushort* __restrict__ xhi,
                ushort* __restrict__ xlo)
{
    size_t i = (size_t)blockIdx.x * 256 + threadIdx.x;
    if (i >= CONVN) return;
    int d = (int)(i % KP);
    size_t row = i / KP;
    ushort h = 0, l = 0;
    if (d < ND) {
        float v = x[row * ND + d];
        h = f2bf(v);
        l = f2bf(v - bf2f(h));
    }
    xhi[i] = h; xlo[i] = l;
}

// ---------------------------------------------------------------------------
// k0v: V [b,t,d] fp32 -> V^T hi/lo bf16 [b, d(80, zero-pad), t(2048)]
// ---------------------------------------------------------------------------
__global__ __launch_bounds__(256)
void k0v_transpose(const float* __restrict__ v, ushort* __restrict__ vthi,
                   ushort* __restrict__ vtlo)
{
    __shared__ float sT[128][66];
    const int tid = threadIdx.x, b = blockIdx.y, t0 = blockIdx.x * 128;
    const float* vb = v + (size_t)b * NS * ND;
    for (int i = tid; i < 128 * ND; i += 256) {
        int t = i / ND, d = i - t * ND;
        sT[t][d] = vb[(size_t)(t0 + t) * ND + d];
    }
    __syncthreads();
    for (int i = tid; i < VD * 128; i += 256) {
        int d = i >> 7, t = i & 127;
        float val = (d < ND) ? sT[t][d] : 0.0f;
        ushort h = f2bf(val);
        ushort l = f2bf(val - bf2f(h));
        size_t o = ((size_t)b * VD + d) * NS + t0 + t;
        vthi[o] = h; vtlo[o] = l;
    }
}

// ---------------------------------------------------------------------------
// k_fused: per (batch, 64-row block), two passes over K (recompute > E
// round-trip):
//  pass A: QK(split-bf16 MFMA) -> acosh -> exp -> rowsum only.
//  pass B: recompute E identically, scale by inv in-register, write final
//    normalized attn ONCE, split P->bf16 hi/lo into LDS (aliases dead B
//    region, barrier-protected), PV via 3-product MFMA vs LDS-staged V^T.
// 8 waves: QK grid (wr2 x wc4); PV grid (prf4 rowfrags x pkh2 k-halves),
// k-half partials reduced through LDS aliasing dead sV.
// Scores in [-4.61, -4.5e-4] => exp without max-subtract == softmax exactly.
// ---------------------------------------------------------------------------
__global__ __launch_bounds__(512, 1)
void k_fused(const ushort* __restrict__ xhi, const ushort* __restrict__ xlo,
             const ushort* __restrict__ vthi, const ushort* __restrict__ vtlo,
             const float* __restrict__ tptr, float* __restrict__ attn,
             float* __restrict__ out)
{
    // 64*KP*2 + 128*KP*2 + 80*136*2 ush + 256 f32 = 124416 B
    __shared__ __align__(16) char smem[124416];
    ushort* sAh = (ushort*)smem;                 // 64 x KP
    ushort* sAl = sAh + 64 * KP;
    ushort* sBh = sAl + 64 * KP;                 // 128 x KP
    ushort* sBl = sBh + 128 * KP;
    ushort* sVh = sBl + 128 * KP;                // 80 x 136
    ushort* sVl = sVh + 80 * 136;
    float*  sSum = (float*)(sVl + 80 * 136);     // [4][64]
    ushort* sPh = sBh;                           // alias: 64x136 <= 128xKP
    ushort* sPl = sBl;
    float*  sRed = (float*)sVh;                  // 2*64*80 f32 = 40960 <= 43520

    const int tid = threadIdx.x;
    const int b  = blockIdx.y;
    const int r0 = blockIdx.x * 64;
    const int lane = tid & 63;
    const int w  = tid >> 6;
    const int wr = w >> 2, wc = w & 3;           // QK: rows 32wr.., cols 32wc..
    const int prf = w & 3, pkh = w >> 2;         // PV: rows 16prf.., k-half
    const float invT = 1.0f / (tptr[0] + 1e-8f);

    const ushort* xhb = xhi + (size_t)b * NS * KP;
    const ushort* xlb = xlo + (size_t)b * NS * KP;
    const ushort* vh = vthi + (size_t)b * VD * NS;
    const ushort* vl = vtlo + (size_t)b * VD * NS;
    float* arow = attn + ((size_t)b * NS + r0) * NS;

    // stage A rows once
    {
        const uint4* sh = (const uint4*)(xhb + (size_t)r0 * KP);
        const uint4* sl = (const uint4*)(xlb + (size_t)r0 * KP);
        uint4* dh = (uint4*)sAh; uint4* dl = (uint4*)sAl;
        for (int i = tid; i < 64 * KP / 8; i += 512) { dh[i] = sh[i]; dl[i] = sl[i]; }
    }
    __syncthreads();
    if (tid < 64) { sAh[tid * KP] ^= 0x8000; sAl[tid * KP] ^= 0x8000; }  // negate time dim

    // ---------------- pass A: rowsums ----------------
    float rsum[2][4];
    #pragma unroll
    for (int rf = 0; rf < 2; ++rf)
        #pragma unroll
        for (int j = 0; j < 4; ++j) rsum[rf][j] = 0.0f;

    for (int ch = 0; ch < 16; ++ch) {
        __syncthreads();
        {
            const uint4* gh = (const uint4*)(xhb + (size_t)ch * 128 * KP);
            const uint4* gl = (const uint4*)(xlb + (size_t)ch * 128 * KP);
            uint4* dh = (uint4*)sBh; uint4* dl = (uint4*)sBl;
            for (int i = tid; i < 128 * KP / 8; i += 512) { dh[i] = gh[i]; dl[i] = gl[i]; }
        }
        __syncthreads();

        f32x4 acc[2][2];
        #pragma unroll
        for (int rf = 0; rf < 2; ++rf)
            #pragma unroll
            for (int cf = 0; cf < 2; ++cf)
                #pragma unroll
                for (int j = 0; j < 4; ++j) acc[rf][cf][j] = 0.0f;

        #pragma unroll
        for (int kc = 0; kc < 3; ++kc) {
            const int koff = kc * 32 + (lane >> 4) * 8;
            short8 ah[2], al[2], bh[2], bl[2];
            #pragma unroll
            for (int rf = 0; rf < 2; ++rf) {
                int ro = (wr * 32 + rf * 16 + (lane & 15)) * KP + koff;
                ah[rf] = *(const short8*)&sAh[ro];
                al[rf] = *(const short8*)&sAl[ro];
            }
            #pragma unroll
            for (int cf = 0; cf < 2; ++cf) {
                int co = (wc * 32 + cf * 16 + (lane & 15)) * KP + koff;
                bh[cf] = *(const short8*)&sBh[co];
                bl[cf] = *(const short8*)&sBl[co];
            }
            #pragma unroll
            for (int rf = 0; rf < 2; ++rf)
                #pragma unroll
                for (int cf = 0; cf < 2; ++cf) {
                    acc[rf][cf] = __builtin_amdgcn_mfma_f32_16x16x32_bf16(ah[rf], bh[cf], acc[rf][cf], 0, 0, 0);
                    acc[rf][cf] = __builtin_amdgcn_mfma_f32_16x16x32_bf16(ah[rf], bl[cf], acc[rf][cf], 0, 0, 0);
                    acc[rf][cf] = __builtin_amdgcn_mfma_f32_16x16x32_bf16(al[rf], bh[cf], acc[rf][cf], 0, 0, 0);
                }
        }

        #pragma unroll
        for (int rf = 0; rf < 2; ++rf)
            #pragma unroll
            for (int cf = 0; cf < 2; ++cf)
                #pragma unroll
                for (int j = 0; j < 4; ++j) {
                    float z = -acc[rf][cf][j];
                    z = fminf(fmaxf(z, 1.0000001f), 50.0f);
                    float dist = __logf(z + __fsqrt_rn(z * z - 1.0f));
                    rsum[rf][j] += __expf(-dist * invT);
                }
    }

    // reduce rowsums: 16 lanes (lane&15) share each row; sum the 4 wc slabs
    #pragma unroll
    for (int rf = 0; rf < 2; ++rf)
        #pragma unroll
        for (int j = 0; j < 4; ++j) {
            float v = rsum[rf][j];
            v += __shfl_xor(v, 1, 64);
            v += __shfl_xor(v, 2, 64);
            v += __shfl_xor(v, 4, 64);
            v += __shfl_xor(v, 8, 64);
            if ((lane & 15) == 0)
                sSum[wc * 64 + wr * 32 + rf * 16 + (lane >> 4) * 4 + j] = v;
        }
    __syncthreads();
    float rinv[2][4];
    #pragma unroll
    for (int rf = 0; rf < 2; ++rf)
        #pragma unroll
        for (int j = 0; j < 4; ++j) {
            int row = wr * 32 + rf * 16 + (lane >> 4) * 4 + j;
            rinv[rf][j] = 1.0f / (sSum[row] + sSum[64 + row] + sSum[128 + row] + sSum[192 + row]);
        }

    // ---------------- pass B: recompute, write attn, PV ----------------
    f32x4 oacc[5];
    #pragma unroll
    for (int f = 0; f < 5; ++f)
        #pragma unroll
        for (int j = 0; j < 4; ++j) oacc[f][j] = 0.0f;

    for (int ch = 0; ch < 16; ++ch) {
        __syncthreads();   // prev PV done reading sP/sV (and sSum reads done)
        {
            const uint4* gh = (const uint4*)(xhb + (size_t)ch * 128 * KP);
            const uint4* gl = (const uint4*)(xlb + (size_t)ch * 128 * KP);
            uint4* dh = (uint4*)sBh; uint4* dl = (uint4*)sBl;
            for (int i = tid; i < 128 * KP / 8; i += 512) { dh[i] = gh[i]; dl[i] = gl[i]; }
        }
        {
            const int kt = ch * 128;
            #pragma unroll
            for (int rep = 0; rep < 3; ++rep) {
                int i = tid + rep * 512;
                if (i < 80 * 16) {
                    int d = i >> 4, c8 = i & 15;
                    size_t go = (size_t)d * NS + kt + c8 * 8;
                    *(short8*)&sVh[d * 136 + c8 * 8] = *(const short8*)&vh[go];
                    *(short8*)&sVl[d * 136 + c8 * 8] = *(const short8*)&vl[go];
                }
            }
        }
        __syncthreads();

        f32x4 acc[2][2];
        #pragma unroll
        for (int rf = 0; rf < 2; ++rf)
            #pragma unroll
            for (int cf = 0; cf < 2; ++cf)
                #pragma unroll
                for (int j = 0; j < 4; ++j) acc[rf][cf][j] = 0.0f;

        #pragma unroll
        for (int kc = 0; kc < 3; ++kc) {
            const int koff = kc * 32 + (lane >> 4) * 8;
            short8 ah[2], al[2], bh[2], bl[2];
            #pragma unroll
            for (int rf = 0; rf < 2; ++rf) {
                int ro = (wr * 32 + rf * 16 + (lane & 15)) * KP + koff;
                ah[rf] = *(const short8*)&sAh[ro];
                al[rf] = *(const short8*)&sAl[ro];
            }
            #pragma unroll
            for (int cf = 0; cf < 2; ++cf) {
                int co = (wc * 32 + cf * 16 + (lane & 15)) * KP + koff;
                bh[cf] = *(const short8*)&sBh[co];
                bl[cf] = *(const short8*)&sBl[co];
            }
            #pragma unroll
            for (int rf = 0; rf < 2; ++rf)
                #pragma unroll
                for (int cf = 0; cf < 2; ++cf) {
                    acc[rf][cf] = __builtin_amdgcn_mfma_f32_16x16x32_bf16(ah[rf], bh[cf], acc[rf][cf], 0, 0, 0);
                    acc[rf][cf] = __builtin_amdgcn_mfma_f32_16x16x32_bf16(ah[rf], bl[cf], acc[rf][cf], 0, 0, 0);
                    acc[rf][cf] = __builtin_amdgcn_mfma_f32_16x16x32_bf16(al[rf], bh[cf], acc[rf][cf], 0, 0, 0);
                }
        }
        __syncthreads();   // all QK reads of sB finished -> safe to overwrite as sP

        #pragma unroll
        for (int rf = 0; rf < 2; ++rf)
            #pragma unroll
            for (int cf = 0; cf < 2; ++cf)
                #pragma unroll
                for (int j = 0; j < 4; ++j) {
                    float z = -acc[rf][cf][j];
                    z = fminf(fmaxf(z, 1.0000001f), 50.0f);
                    float dist = __logf(z + __fsqrt_rn(z * z - 1.0f));
                    float en = __expf(-dist * invT) * rinv[rf][j];
                    int row  = wr * 32 + rf * 16 + (lane >> 4) * 4 + j;
                    int colc = wc * 32 + cf * 16 + (lane & 15);
                    arow[(size_t)row * NS + ch * 128 + colc] = en;
                    ushort h = f2bf(en);
                    sPh[row * 136 + colc] = h;
                    sPl[row * 136 + colc] = f2bf(en - bf2f(h));
                }
        __syncthreads();   // sP visible

        #pragma unroll
        for (int ks = 0; ks < 2; ++ks) {
            const int koff = pkh * 64 + ks * 32 + (lane >> 4) * 8;
            short8 ph = *(const short8*)&sPh[(prf * 16 + (lane & 15)) * 136 + koff];
            short8 pl = *(const short8*)&sPl[(prf * 16 + (lane & 15)) * 136 + koff];
            #pragma unroll
            for (int f = 0; f < 5; ++f) {
                int vo = (f * 16 + (lane & 15)) * 136 + koff;
                short8 bh = *(const short8*)&sVh[vo];
                short8 bl = *(const short8*)&sVl[vo];
                oacc[f] = __builtin_amdgcn_mfma_f32_16x16x32_bf16(ph, bh, oacc[f], 0, 0, 0);
                oacc[f] = __builtin_amdgcn_mfma_f32_16x16x32_bf16(ph, bl, oacc[f], 0, 0, 0);
                oacc[f] = __builtin_amdgcn_mfma_f32_16x16x32_bf16(pl, bh, oacc[f], 0, 0, 0);
            }
        }
    }

    __syncthreads();   // PV done -> sV region reusable as sRed
    #pragma unroll
    for (int f = 0; f < 5; ++f)
        #pragma unroll
        for (int j = 0; j < 4; ++j) {
            int r = prf * 16 + (lane >> 4) * 4 + j;
            int d = f * 16 + (lane & 15);
            sRed[(size_t)pkh * 64 * 80 + (size_t)r * 80 + d] = oacc[f][j];
        }
    __syncthreads();
    for (int i = tid; i < 64 * 80; i += 512) {
        int r = i / 80, d = i - r * 80;
        float s = sRed[i] + sRed[64 * 80 + i];
        if (d < ND) out[((size_t)b * NS + r0 + r) * ND + d] = s;
    }
}

extern "C" void kernel_launch(void* const* d_in, const int* in_sizes, int n_in,
                              void* d_out, int out_size, void* d_ws, size_t ws_size,
                              hipStream_t stream) {
    const float* x      = (const float*)d_in[0];
    const float* values = (const float*)d_in[1];
    const float* temp   = (const float*)d_in[2];

    float* out  = (float*)d_out;
    float* attn = out + OUTSZ;

    ushort* xhi  = (ushort*)d_ws;
    ushort* xlo  = xhi + CONVN;
    ushort* vthi = xlo + CONVN;
    ushort* vtlo = vthi + VTN;

    k0_convert<<<(int)((CONVN + 255) / 256), 256, 0, stream>>>(x, xhi, xlo);
    k0v_transpose<<<dim3(NS / 128, NB), 256, 0, stream>>>(values, vthi, vtlo);

    k_fused<<<dim3(NS / 64, NB), 512, 0, stream>>>(xhi, xlo, vthi, vtlo, temp, attn, out);
}

// Round 8
// 144.470 us; speedup vs baseline: 1.2497x; 1.2497x over previous
//
#include <hip/hip_runtime.h>
#include <math.h>

constexpr int NB = 8, NS = 2048, ND = 65;
constexpr int KP = 104;     // padded K stride for x conv (bf16 elems)
constexpr int VD = 80;      // padded d rows for V^T
constexpr size_t OUTSZ = (size_t)NB * NS * ND;
constexpr size_t CONVN = (size_t)NB * NS * KP;   // x conv elems per array
constexpr size_t VTN   = (size_t)NB * VD * NS;   // V^T elems per array

typedef short short8 __attribute__((ext_vector_type(8)));
typedef float f32x4 __attribute__((ext_vector_type(4)));

__device__ __forceinline__ ushort f2bf(float f) {
    uint u = __float_as_uint(f);
    return (ushort)((u + 0x7fffu + ((u >> 16) & 1u)) >> 16);   // RNE
}
__device__ __forceinline__ float bf2f(ushort h) {
    return __uint_as_float((uint)h << 16);
}

// ---------------------------------------------------------------------------
// k0x: x fp32 -> (hi, lo) bf16 split arrays, K padded 65->104 with zeros.
// ---------------------------------------------------------------------------
__global__ __launch_bounds__(256)
void k0_convert(const float* __restrict__ x, ushort* __restrict__ xhi,
                ushort* __restrict__ xlo)
{
    size_t i = (size_t)blockIdx.x * 256 + threadIdx.x;
    if (i >= CONVN) return;
    int d = (int)(i % KP);
    size_t row = i / KP;
    ushort h = 0, l = 0;
    if (d < ND) {
        float v = x[row * ND + d];
        h = f2bf(v);
        l = f2bf(v - bf2f(h));
    }
    xhi[i] = h; xlo[i] = l;
}

// ---------------------------------------------------------------------------
// k0v: V [b,t,d] fp32 -> V^T hi/lo bf16 [b, d(80, zero-pad), t(2048)]
// ---------------------------------------------------------------------------
__global__ __launch_bounds__(256)
void k0v_transpose(const float* __restrict__ v, ushort* __restrict__ vthi,
                   ushort* __restrict__ vtlo)
{
    __shared__ float sT[128][66];
    const int tid = threadIdx.x, b = blockIdx.y, t0 = blockIdx.x * 128;
    const float* vb = v + (size_t)b * NS * ND;
    for (int i = tid; i < 128 * ND; i += 256) {
        int t = i / ND, d = i - t * ND;
        sT[t][d] = vb[(size_t)(t0 + t) * ND + d];
    }
    __syncthreads();
    for (int i = tid; i < VD * 128; i += 256) {
        int d = i >> 7, t = i & 127;
        float val = (d < ND) ? sT[t][d] : 0.0f;
        ushort h = f2bf(val);
        ushort l = f2bf(val - bf2f(h));
        size_t o = ((size_t)b * VD + d) * NS + t0 + t;
        vthi[o] = h; vtlo[o] = l;
    }
}

// ---------------------------------------------------------------------------
// k1: per (batch, 64-row block): S via split-bf16 MFMA (hi*hi+hi*lo+lo*hi),
// E = exp(-acosh(clip)/T) written fp32 unnormalized, inv[row] -> ws.
// TC=128 single-buffered => LDS 80.9 KB => 2 blocks/CU (16 waves) so barrier
// drains hide across blocks. Epilogue stores cf-innermost (line-adjacent).
// Scores in [-4.61, -4.5e-4] => exp without max-subtract == softmax exactly.
// ---------------------------------------------------------------------------
__global__ __launch_bounds__(512, 4)
void k1_scores(const ushort* __restrict__ xhi, const ushort* __restrict__ xlo,
               const float* __restrict__ tptr, float* __restrict__ attn,
               float* __restrict__ invb)
{
    __shared__ __align__(16) ushort sAh[64 * KP], sAl[64 * KP];
    __shared__ __align__(16) ushort sBh[128 * KP], sBl[128 * KP];
    __shared__ float sSum[4][64];

    const int tid = threadIdx.x;
    const int b  = blockIdx.y;
    const int r0 = blockIdx.x * 64;
    const int lane = tid & 63;
    const int w  = tid >> 6;
    const int wr = w >> 2;          // 0..1  (32-row slab)
    const int wc = w & 3;           // 0..3  (32-col slab)
    const float invT = 1.0f / (tptr[0] + 1e-8f);

    const ushort* xhb = xhi + (size_t)b * NS * KP;
    const ushort* xlb = xlo + (size_t)b * NS * KP;
    float* arow = attn + ((size_t)b * NS + r0) * NS;

    {
        const uint4* sh = (const uint4*)(xhb + (size_t)r0 * KP);
        const uint4* sl = (const uint4*)(xlb + (size_t)r0 * KP);
        uint4* dh = (uint4*)sAh; uint4* dl = (uint4*)sAl;
        for (int i = tid; i < 64 * KP / 8; i += 512) { dh[i] = sh[i]; dl[i] = sl[i]; }
    }
    __syncthreads();
    if (tid < 64) { sAh[tid * KP] ^= 0x8000; sAl[tid * KP] ^= 0x8000; }  // negate time dim

    float rsum[2][4];
    #pragma unroll
    for (int rf = 0; rf < 2; ++rf)
        #pragma unroll
        for (int j = 0; j < 4; ++j) rsum[rf][j] = 0.0f;

    for (int tc = 0; tc < NS; tc += 128) {
        __syncthreads();
        {
            const uint4* gh = (const uint4*)(xhb + (size_t)tc * KP);
            const uint4* gl = (const uint4*)(xlb + (size_t)tc * KP);
            uint4* dh = (uint4*)sBh; uint4* dl = (uint4*)sBl;
            for (int i = tid; i < 128 * KP / 8; i += 512) { dh[i] = gh[i]; dl[i] = gl[i]; }
        }
        __syncthreads();

        f32x4 acc[2][2];
        #pragma unroll
        for (int rf = 0; rf < 2; ++rf)
            #pragma unroll
            for (int cf = 0; cf < 2; ++cf)
                #pragma unroll
                for (int j = 0; j < 4; ++j) acc[rf][cf][j] = 0.0f;

        #pragma unroll
        for (int kc = 0; kc < 3; ++kc) {
            const int koff = kc * 32 + (lane >> 4) * 8;
            short8 ah[2], al[2], bh[2], bl[2];
            #pragma unroll
            for (int rf = 0; rf < 2; ++rf) {
                int ro = (wr * 32 + rf * 16 + (lane & 15)) * KP + koff;
                ah[rf] = *(const short8*)&sAh[ro];
                al[rf] = *(const short8*)&sAl[ro];
            }
            #pragma unroll
            for (int cf = 0; cf < 2; ++cf) {
                int co = (wc * 32 + cf * 16 + (lane & 15)) * KP + koff;
                bh[cf] = *(const short8*)&sBh[co];
                bl[cf] = *(const short8*)&sBl[co];
            }
            #pragma unroll
            for (int rf = 0; rf < 2; ++rf)
                #pragma unroll
                for (int cf = 0; cf < 2; ++cf) {
                    acc[rf][cf] = __builtin_amdgcn_mfma_f32_16x16x32_bf16(ah[rf], bh[cf], acc[rf][cf], 0, 0, 0);
                    acc[rf][cf] = __builtin_amdgcn_mfma_f32_16x16x32_bf16(ah[rf], bl[cf], acc[rf][cf], 0, 0, 0);
                    acc[rf][cf] = __builtin_amdgcn_mfma_f32_16x16x32_bf16(al[rf], bh[cf], acc[rf][cf], 0, 0, 0);
                }
        }

        // epilogue: compute all e first, then line-adjacent stores (cf inner)
        float ev[2][2][4];
        #pragma unroll
        for (int rf = 0; rf < 2; ++rf)
            #pragma unroll
            for (int cf = 0; cf < 2; ++cf)
                #pragma unroll
                for (int j = 0; j < 4; ++j) {
                    float z = -acc[rf][cf][j];
                    z = fminf(fmaxf(z, 1.0000001f), 50.0f);
                    float dist = __logf(z + __fsqrt_rn(z * z - 1.0f));
                    float e = __expf(-dist * invT);
                    ev[rf][cf][j] = e;
                    rsum[rf][j] += e;
                }
        #pragma unroll
        for (int rf = 0; rf < 2; ++rf)
            #pragma unroll
            for (int j = 0; j < 4; ++j) {
                int row = wr * 32 + rf * 16 + (lane >> 4) * 4 + j;
                #pragma unroll
                for (int cf = 0; cf < 2; ++cf) {
                    int col = tc + wc * 32 + cf * 16 + (lane & 15);
                    arow[(size_t)row * NS + col] = ev[rf][cf][j];
                }
            }
    }

    // deterministic row-sum reduce: 16 lanes (lane&15) share each row
    #pragma unroll
    for (int rf = 0; rf < 2; ++rf)
        #pragma unroll
        for (int j = 0; j < 4; ++j) {
            float v = rsum[rf][j];
            v += __shfl_xor(v, 1, 64);
            v += __shfl_xor(v, 2, 64);
            v += __shfl_xor(v, 4, 64);
            v += __shfl_xor(v, 8, 64);
            if ((lane & 15) == 0)
                sSum[wc][wr * 32 + rf * 16 + (lane >> 4) * 4 + j] = v;
        }
    __syncthreads();
    if (tid < 64)
        invb[(size_t)b * NS + r0 + tid] =
            1.0f / (sSum[0][tid] + sSum[1][tid] + sSum[2][tid] + sSum[3][tid]);
}

// ---------------------------------------------------------------------------
// k2: per (batch, 32-row block, k-half): read E (L3-hot), normalize, write
// attn in place, bf16-split into LDS; stage V^T [80][64] chunk hi/lo; MFMA.
// 4 waves = 2 row-halves x 2 k-slices. chunk=64 => LDS 32.4 KB => 4 blocks/CU.
// Partial O (per k-half) -> ws; k3 reduces the two halves.
// ---------------------------------------------------------------------------
__global__ __launch_bounds__(256, 4)
void k2_pv(float* __restrict__ attn, const ushort* __restrict__ vthi,
           const ushort* __restrict__ vtlo, const float* __restrict__ invb,
           float* __restrict__ part)
{
    __shared__ __align__(16) ushort sAh[32 * 72], sAl[32 * 72];   // 9216 B
    __shared__ __align__(16) char svmem[VD * 72 * 2 * 2];          // 23040 B
    ushort* sVh = (ushort*)svmem;
    ushort* sVl = sVh + VD * 72;
    float*  sRed = (float*)svmem;          // 2*32*80 f32 = 20480 <= 23040
    __shared__ float sInvL[32];

    const int tid = threadIdx.x;
    const int b  = blockIdx.y;
    const int r0 = blockIdx.x * 32;
    const int kt0 = blockIdx.z * (NS / 2);
    const int lane = tid & 63;
    const int w = tid >> 6;
    const int wr = w >> 1;            // row-half (16 rows)
    const int wk = w & 1;             // k-slice (32 of 64)

    if (tid < 32) sInvL[tid] = invb[(size_t)b * NS + r0 + tid];

    float* arow = attn + ((size_t)b * NS + r0) * NS;
    const ushort* vh = vthi + (size_t)b * VD * NS;
    const ushort* vl = vtlo + (size_t)b * VD * NS;

    f32x4 acc[5];
    #pragma unroll
    for (int f = 0; f < 5; ++f)
        #pragma unroll
        for (int j = 0; j < 4; ++j) acc[f][j] = 0.0f;

    __syncthreads();

    for (int kk = 0; kk < NS / 2; kk += 64) {
        const int kt = kt0 + kk;
        // stage E: 32 rows x 16 float4; RMW normalize + bf16 split into sA
        #pragma unroll
        for (int rep = 0; rep < 2; ++rep) {
            int idx = tid + rep * 256;          // 512 = 32 rows x 16 float4
            int row = idx >> 4, c4 = idx & 15;
            float4* p = (float4*)&arow[(size_t)row * NS + kt + c4 * 4];
            float4 e = *p;
            float inv = sInvL[row];
            e.x *= inv; e.y *= inv; e.z *= inv; e.w *= inv;
            *p = e;
            ushort h0 = f2bf(e.x), h1 = f2bf(e.y), h2 = f2bf(e.z), h3 = f2bf(e.w);
            ushort l0 = f2bf(e.x - bf2f(h0)), l1 = f2bf(e.y - bf2f(h1));
            ushort l2 = f2bf(e.z - bf2f(h2)), l3 = f2bf(e.w - bf2f(h3));
            int so = row * 72 + c4 * 4;
            *(ushort4*)&sAh[so] = make_ushort4(h0, h1, h2, h3);
            *(ushort4*)&sAl[so] = make_ushort4(l0, l1, l2, l3);
        }
        // stage V^T chunk [80][64] hi/lo: 640 short8 per array
        #pragma unroll
        for (int rep = 0; rep < 3; ++rep) {
            int i = tid + rep * 256;
            if (i < VD * 8) {
                int d = i >> 3, c8 = i & 7;
                size_t go = (size_t)d * NS + kt + c8 * 8;
                *(short8*)&sVh[d * 72 + c8 * 8] = *(const short8*)&vh[go];
                *(short8*)&sVl[d * 72 + c8 * 8] = *(const short8*)&vl[go];
            }
        }
        __syncthreads();

        const int koff = wk * 32 + (lane >> 4) * 8;
        short8 ah = *(const short8*)&sAh[(wr * 16 + (lane & 15)) * 72 + koff];
        short8 al = *(const short8*)&sAl[(wr * 16 + (lane & 15)) * 72 + koff];
        #pragma unroll
        for (int f = 0; f < 5; ++f) {
            int vo = (f * 16 + (lane & 15)) * 72 + koff;
            short8 bh = *(const short8*)&sVh[vo];
            short8 bl = *(const short8*)&sVl[vo];
            acc[f] = __builtin_amdgcn_mfma_f32_16x16x32_bf16(ah, bh, acc[f], 0, 0, 0);
            acc[f] = __builtin_amdgcn_mfma_f32_16x16x32_bf16(ah, bl, acc[f], 0, 0, 0);
            acc[f] = __builtin_amdgcn_mfma_f32_16x16x32_bf16(al, bh, acc[f], 0, 0, 0);
        }
        __syncthreads();   // protect sA/sV rewrite next chunk
    }

    // reduce the 2 k-slices via sRed (aliases dead sV region)
    #pragma unroll
    for (int f = 0; f < 5; ++f)
        #pragma unroll
        for (int j = 0; j < 4; ++j) {
            int r = wr * 16 + (lane >> 4) * 4 + j;
            int d = f * 16 + (lane & 15);
            sRed[(size_t)wk * 32 * VD + (size_t)r * VD + d] = acc[f][j];
        }
    __syncthreads();
    float* dst = part + (size_t)blockIdx.z * OUTSZ;
    for (int i = tid; i < 32 * VD; i += 256) {
        int r = i / VD, d = i - r * VD;
        float s = sRed[i] + sRed[32 * VD + i];
        if (d < ND) dst[((size_t)b * NS + r0 + r) * ND + d] = s;
    }
}

// ---------------------------------------------------------------------------
// k3: out = part[0] + part[1] (deterministic)
// ---------------------------------------------------------------------------
__global__ __launch_bounds__(256)
void k3_reduce(const float* __restrict__ part, float* __restrict__ out)
{
    const size_t n4 = OUTSZ / 4;
    size_t i = (size_t)blockIdx.x * 256 + threadIdx.x;
    if (i >= n4) return;
    const float4* p4 = (const float4*)part;
    float4 a = p4[i], c = p4[i + n4];
    a.x += c.x; a.y += c.y; a.z += c.z; a.w += c.w;
    ((float4*)out)[i] = a;
}

extern "C" void kernel_launch(void* const* d_in, const int* in_sizes, int n_in,
                              void* d_out, int out_size, void* d_ws, size_t ws_size,
                              hipStream_t stream) {
    const float* x      = (const float*)d_in[0];
    const float* values = (const float*)d_in[1];
    const float* temp   = (const float*)d_in[2];

    float* out  = (float*)d_out;
    float* attn = out + OUTSZ;

    // ws layout: [vthi][vtlo][invb][xhi][xlo ...]; k2's partials overlay the
    // dead xhi/xlo region (k1 consumed them; k0 rewrites every call).
    // Touched: 5.24 MB (vt) + 0.26 MB (invb) + 8.52 MB (partials) = 13.8 MB.
    ushort* vthi = (ushort*)d_ws;
    ushort* vtlo = vthi + VTN;
    float*  invb = (float*)(vtlo + VTN);
    ushort* xhi  = (ushort*)(invb + (size_t)NB * NS);
    ushort* xlo  = xhi + CONVN;
    float*  part = (float*)xhi;          // 2 * OUTSZ floats

    k0_convert<<<(int)((CONVN + 255) / 256), 256, 0, stream>>>(x, xhi, xlo);
    k0v_transpose<<<dim3(NS / 128, NB), 256, 0, stream>>>(values, vthi, vtlo);

    k1_scores<<<dim3(NS / 64, NB), 512, 0, stream>>>(xhi, xlo, temp, attn, invb);
    k2_pv<<<dim3(NS / 32, NB, 2), 256, 0, stream>>>(attn, vthi, vtlo, invb, part);
    k3_reduce<<<(int)((OUTSZ / 4 + 255) / 256), 256, 0, stream>>>(part, out);
}